// Round 2
// baseline (18618.640 us; speedup 1.0000x reference)
//
#include <hip/hip_runtime.h>

#define HH 50
#define NG 200        // 4*H gate rows
#define NB 4          // batch elements per block
#define TT 512
#define NTH 512
#define V0S 60        // s_v0 row stride: [x0 x1 x2 | h0(50) | pad(3) | pad-to-60]; 60*4=240 (16B-mult)
#define L1S 104       // s_l1 row stride: [h1_t(50) pad(2) | hB(50) pad(2)]; 52*4=208, 104*4=416 (16B-mult)

__device__ __forceinline__ float fast_sigmoid(float x) {
    x = fminf(fmaxf(x, -30.f), 30.f);
    return 1.f / (1.f + __expf(-x));
}
__device__ __forceinline__ float fast_tanh(float x) {
    x = fminf(fmaxf(x, -15.f), 15.f);
    float e = __expf(2.f * x);
    return (e - 1.f) / (e + 1.f);
}

// Split-row persistent-weight LSTM:
//  - lane pair (2j, 2j+1) owns gate row j; each lane holds HALF the row's weights
//    in registers (28 + 52 floats), pinned via empty inline asm so the backend
//    cannot rematerialize the global loads inside the t-loop (round-1 failure mode:
//    VGPR=104 + per-step L1/L2 weight reloads).
//  - uniform code across halves: zero-padded weights + base offsets, no intra-wave branch.
__global__ __launch_bounds__(NTH, 4) void lstm_fused_v2(
    const float* __restrict__ x,
    const float* __restrict__ W_ih0, const float* __restrict__ W_hh0,
    const float* __restrict__ b_ih0, const float* __restrict__ b_hh0,
    const float* __restrict__ W_ih1, const float* __restrict__ W_hh1,
    const float* __restrict__ b_ih1, const float* __restrict__ b_hh1,
    const float* __restrict__ fc_w, const float* __restrict__ fc_b,
    float* __restrict__ out)
{
    __shared__ float s_x[NB * TT * 3];   // 24 KB staged input
    __shared__ float s_v0[NB * V0S];     // layer0 matvec input: [x_t | h0 | pad]
    __shared__ float s_l1[NB * L1S];     // layer1 matvec input: [h1_t | pad | hB | pad]
    __shared__ float s_g[NB * NG];       // gate preactivations

    const int tid  = threadIdx.x;
    const int b0   = blockIdx.x * NB;
    const int j    = tid >> 1;           // gate row, active when < 200
    const int half = tid & 1;

    // ---- stage x (coalesced), zero LDS state ----
    for (int i = tid; i < NB * TT * 3; i += NTH) {
        int bb = i / (TT * 3);
        int r  = i - bb * (TT * 3);
        s_x[i] = x[(size_t)(b0 + bb) * (TT * 3) + r];
    }
    for (int i = tid; i < NB * V0S; i += NTH) s_v0[i] = 0.f;
    for (int i = tid; i < NB * L1S; i += NTH) s_l1[i] = 0.f;

    // ---- per-lane half-row weights into registers ----
    float w0[28];          // layer0: half0=[Wih0(3) | Whh0 k0..24]; half1=[Whh0 k25..49 | 0,0,0]
    float w1[52];          // layer1: half0=Wih1 row + 0,0 ; half1=Whh1 row + 0,0
    float bias0h = 0.f, bias1h = 0.f;
    {
        const int jr = min(j, NG - 1);
        if (half == 0) {
            w0[0] = W_ih0[jr * 3 + 0];
            w0[1] = W_ih0[jr * 3 + 1];
            w0[2] = W_ih0[jr * 3 + 2];
            #pragma unroll
            for (int k = 0; k < 25; ++k) w0[3 + k] = W_hh0[jr * HH + k];
            #pragma unroll
            for (int k = 0; k < 50; ++k) w1[k] = W_ih1[jr * HH + k];
            bias0h = b_ih0[jr] + b_hh0[jr];
            bias1h = b_ih1[jr] + b_hh1[jr];
        } else {
            #pragma unroll
            for (int k = 0; k < 25; ++k) w0[k] = W_hh0[jr * HH + 25 + k];
            w0[25] = 0.f; w0[26] = 0.f; w0[27] = 0.f;
            #pragma unroll
            for (int k = 0; k < 50; ++k) w1[k] = W_hh1[jr * HH + k];
        }
        w1[50] = 0.f; w1[51] = 0.f;
    }
    // Pin weights into VGPRs: opaque asm def kills load-rematerialization.
    #pragma unroll
    for (int k = 0; k < 28; ++k) asm volatile("" : "+v"(w0[k]));
    #pragma unroll
    for (int k = 0; k < 52; ++k) asm volatile("" : "+v"(w1[k]));
    asm volatile("" : "+v"(bias0h));
    asm volatile("" : "+v"(bias1h));

    // cell-update role: thread (cb, cu) owns c-state in registers (tid < 200)
    const int cb = tid / HH;
    const int cu = tid - cb * HH;
    float c0 = 0.f, cB = 0.f;

    __syncthreads();
    // seed x(t=0) into s_v0
    if (tid < NB * 3) {
        int bb = tid / 3, c = tid - bb * 3;
        s_v0[bb * V0S + c] = s_x[(bb * TT + 0) * 3 + c];
    }
    __syncthreads();

    const int vb0 = half * 28;   // layer0 read base within s_v0 row
    const int vb1 = half * 52;   // layer1 read base within s_l1 row

    for (int t = 0; t < TT; ++t) {
        // ---- phase 1: layer0 half-row matvec ----
        if (j < NG) {
            float acc[NB];
            #pragma unroll
            for (int b = 0; b < NB; ++b) acc[b] = bias0h;
            #pragma unroll
            for (int q = 0; q < 7; ++q) {
                #pragma unroll
                for (int b = 0; b < NB; ++b) {
                    const float4 v = *(const float4*)&s_v0[b * V0S + vb0 + q * 4];
                    acc[b] += w0[q * 4 + 0] * v.x + w0[q * 4 + 1] * v.y
                            + w0[q * 4 + 2] * v.z + w0[q * 4 + 3] * v.w;
                }
            }
            #pragma unroll
            for (int b = 0; b < NB; ++b) {
                acc[b] += __shfl_xor(acc[b], 1, 64);
                if (half == 0) s_g[b * NG + j] = acc[b];
            }
        }
        __syncthreads();
        // ---- phase 2: layer0 cell (+ stage x_{t+1}) ----
        if (tid < NB * HH) {
            float gi = fast_sigmoid(s_g[cb * NG + cu]);
            float gf = fast_sigmoid(s_g[cb * NG + cu + HH]);
            float gg = fast_tanh  (s_g[cb * NG + cu + 2 * HH]);
            float go = fast_sigmoid(s_g[cb * NG + cu + 3 * HH]);
            c0 = gf * c0 + gi * gg;
            float h = go * fast_tanh(c0);
            s_v0[cb * V0S + 3 + cu] = h;
            s_l1[cb * L1S + cu]     = h;
        } else if (tid < NB * HH + NB * 3) {
            if (t + 1 < TT) {
                int i2 = tid - NB * HH;
                int bb = i2 / 3, c = i2 - bb * 3;
                s_v0[bb * V0S + c] = s_x[(bb * TT + t + 1) * 3 + c];
            }
        }
        __syncthreads();
        // ---- phase 3: layer1 half-row matvec ----
        if (j < NG) {
            float acc[NB];
            #pragma unroll
            for (int b = 0; b < NB; ++b) acc[b] = bias1h;
            #pragma unroll
            for (int q = 0; q < 13; ++q) {
                #pragma unroll
                for (int b = 0; b < NB; ++b) {
                    const float4 v = *(const float4*)&s_l1[b * L1S + vb1 + q * 4];
                    acc[b] += w1[q * 4 + 0] * v.x + w1[q * 4 + 1] * v.y
                            + w1[q * 4 + 2] * v.z + w1[q * 4 + 3] * v.w;
                }
            }
            #pragma unroll
            for (int b = 0; b < NB; ++b) {
                acc[b] += __shfl_xor(acc[b], 1, 64);
                if (half == 0) s_g[b * NG + j] = acc[b];
            }
        }
        __syncthreads();
        // ---- phase 4: layer1 cell ----
        if (tid < NB * HH) {
            float gi = fast_sigmoid(s_g[cb * NG + cu]);
            float gf = fast_sigmoid(s_g[cb * NG + cu + HH]);
            float gg = fast_tanh  (s_g[cb * NG + cu + 2 * HH]);
            float go = fast_sigmoid(s_g[cb * NG + cu + 3 * HH]);
            cB = gf * cB + gi * gg;
            float h = go * fast_tanh(cB);
            s_l1[cb * L1S + 52 + cu] = h;
        }
        __syncthreads();
    }

    // ---- final FC: out[b] = hB[b] @ fc_w.T + fc_b ----
    if (tid < NB * 3) {
        int bb = tid / 3, o = tid - bb * 3;
        float accv = fc_b[o];
        #pragma unroll
        for (int u = 0; u < HH; ++u)
            accv += s_l1[bb * L1S + 52 + u] * fc_w[o * HH + u];
        out[(size_t)(b0 + bb) * 3 + o] = accv;
    }
}

extern "C" void kernel_launch(void* const* d_in, const int* in_sizes, int n_in,
                              void* d_out, int out_size, void* d_ws, size_t ws_size,
                              hipStream_t stream) {
    const float* x     = (const float*)d_in[0];
    const float* W_ih0 = (const float*)d_in[1];
    const float* W_hh0 = (const float*)d_in[2];
    const float* b_ih0 = (const float*)d_in[3];
    const float* b_hh0 = (const float*)d_in[4];
    const float* W_ih1 = (const float*)d_in[5];
    const float* W_hh1 = (const float*)d_in[6];
    const float* b_ih1 = (const float*)d_in[7];
    const float* b_hh1 = (const float*)d_in[8];
    const float* fc_w  = (const float*)d_in[9];
    const float* fc_b  = (const float*)d_in[10];
    float* out = (float*)d_out;

    const int B = 2048;
    dim3 grid(B / NB), block(NTH);
    lstm_fused_v2<<<grid, block, 0, stream>>>(
        x, W_ih0, W_hh0, b_ih0, b_hh0, W_ih1, W_hh1, b_ih1, b_hh1, fc_w, fc_b, out);
}

// Round 3
// 1624.628 us; speedup vs baseline: 11.4602x; 11.4602x over previous
//
#include <hip/hip_runtime.h>

#define HH 50
#define NGATE 200      // 4*H gate rows
#define NB 8           // batch elements per block (M of the MFMA tile; rows 8-15 zero)
#define TT 512
#define NTH 512
#define NTILES 13      // ceil(200/16) N-tiles
#define A0S 72         // A0 row stride in shorts (64 k + 8 pad) = 144 B
#define A1S 136        // A1 row stride in shorts (128 k + 8 pad) = 272 B
#define GS 20          // g (transposed [n][m]) row stride in floats = 80 B

typedef __attribute__((ext_vector_type(8))) short short8;
typedef __attribute__((ext_vector_type(4))) float f32x4;

__device__ __forceinline__ unsigned short f2bf(float f) {
    unsigned int u = __float_as_uint(f);
    u += 0x7FFFu + ((u >> 16) & 1u);          // round-to-nearest-even
    return (unsigned short)(u >> 16);
}
__device__ __forceinline__ float bf2f(unsigned short s) {
    return __uint_as_float(((unsigned int)s) << 16);
}
__device__ __forceinline__ float fast_sigmoid(float v) {
    v = fminf(fmaxf(v, -30.f), 30.f);
    return 1.f / (1.f + __expf(-v));
}
__device__ __forceinline__ float fast_tanh(float v) {
    v = fminf(fmaxf(v, -15.f), 15.f);
    float e = __expf(2.f * v);
    return (e - 1.f) / (e + 1.f);
}

// LDS: big staging buffer (weights, pre-loop) unioned with steady-state buffers.
// Weight B-fragments are read FROM LDS into VGPRs: since LDS is written every
// step afterwards, the compiler cannot sink/remat those loads into the t-loop
// (round-1 failure), and no asm pinning is needed (round-2 failure).
union Shm {
    float wstage[200 * 104 + 64];             // 83.7 KB staging
    struct {
        unsigned short A0hi[16 * A0S];        // layer0 A (h0), bf16 hi
        unsigned short A0lo[16 * A0S];
        unsigned short A1hi[16 * A1S];        // layer1 A ([h1_t | hB]), bf16 hi
        unsigned short A1lo[16 * A1S];
        float g[208 * GS];                    // gate preacts, transposed [n][m]
        float hBf[8 * 52];                    // final-step hB, fp32 for FC
    } s;
};

__global__ __launch_bounds__(NTH, 2) void lstm_mfma(
    const float* __restrict__ x,
    const float* __restrict__ W_ih0, const float* __restrict__ W_hh0,
    const float* __restrict__ b_ih0, const float* __restrict__ b_hh0,
    const float* __restrict__ W_ih1, const float* __restrict__ W_hh1,
    const float* __restrict__ b_ih1, const float* __restrict__ b_hh1,
    const float* __restrict__ fc_w, const float* __restrict__ fc_b,
    float* __restrict__ out)
{
    __shared__ Shm u;

    const int tid = threadIdx.x;
    const int lane = tid & 63;
    const int wid = tid >> 6;          // wave id 0..7; owns N-tiles {wid, wid+8}
    const int n16 = lane & 15;         // MFMA 16-dim index (A: m, B: n, C: col)
    const int q4 = lane >> 4;          // MFMA quad index
    const int b0 = blockIdx.x * NB;

    // ---- S1: stage biases + W_ih0, preload cell-role constants ----
    for (int i = tid; i < 1400; i += NTH) {
        float v;
        if (i < 200)      v = b_ih0[i];
        else if (i < 400) v = b_hh0[i - 200];
        else if (i < 600) v = b_ih1[i - 400];
        else if (i < 800) v = b_hh1[i - 600];
        else              v = W_ih0[i - 800];
        u.wstage[i] = v;
    }
    __syncthreads();

    const int cb = tid & 7;            // cell role: batch
    const int cu = tid >> 3;           // cell role: hidden unit
    const bool cellAct = (tid < NB * HH);
    float bias0g[4] = {0.f, 0.f, 0.f, 0.f};
    float bias1g[4] = {0.f, 0.f, 0.f, 0.f};
    float wx[4][3] = {{0.f,0.f,0.f},{0.f,0.f,0.f},{0.f,0.f,0.f},{0.f,0.f,0.f}};
    if (cellAct) {
        #pragma unroll
        for (int g4 = 0; g4 < 4; ++g4) {
            int j = cu + 50 * g4;
            bias0g[g4] = u.wstage[j] + u.wstage[200 + j];
            bias1g[g4] = u.wstage[400 + j] + u.wstage[600 + j];
            wx[g4][0] = u.wstage[800 + j * 3 + 0];
            wx[g4][1] = u.wstage[800 + j * 3 + 1];
            wx[g4][2] = u.wstage[800 + j * 3 + 2];
        }
    }
    __syncthreads();

    // ---- S2: stage W_hh0 as [200][52], extract layer0 B-fragments ----
    for (int i = tid; i < 200 * 52; i += NTH) {
        int r = i / 52, c = i - r * 52;
        u.wstage[i] = (c < 50) ? W_hh0[r * 50 + c] : 0.f;
    }
    __syncthreads();
    short8 b0h[2][2], b0l[2][2];
    #pragma unroll
    for (int ti = 0; ti < 2; ++ti) {
        int nt = wid + ti * 8;
        int n = nt * 16 + n16;
        int nc = (n < NGATE) ? n : 0;
        bool valid = (nt < NTILES) && (n < NGATE);
        #pragma unroll
        for (int kt = 0; kt < 2; ++kt) {
            int base = nc * 52 + kt * 32 + q4 * 8;
            f32x4 wa = *(const f32x4*)&u.wstage[base];
            f32x4 wb = *(const f32x4*)&u.wstage[base + 4];
            short8 hi, lo;
            #pragma unroll
            for (int jj = 0; jj < 8; ++jj) {
                int kk = kt * 32 + q4 * 8 + jj;
                float w = (valid && kk < 50) ? ((jj < 4) ? wa[jj] : wb[jj - 4]) : 0.f;
                unsigned short h = f2bf(w);
                hi[jj] = (short)h;
                lo[jj] = (short)f2bf(w - bf2f(h));
            }
            b0h[ti][kt] = hi;
            b0l[ti][kt] = lo;
        }
    }
    __syncthreads();

    // ---- S3: stage [W_ih1 | W_hh1] as [200][104], extract layer1 B-fragments ----
    for (int i = tid; i < 200 * 104; i += NTH) {
        int r = i / 104, c = i - r * 104;
        float v = 0.f;
        if (c < 50)       v = W_ih1[r * 50 + c];
        else if (c < 100) v = W_hh1[r * 50 + (c - 50)];
        u.wstage[i] = v;
    }
    if (tid < 64) u.wstage[200 * 104 + tid] = 0.f;
    __syncthreads();
    short8 b1h[2][4], b1l[2][4];
    #pragma unroll
    for (int ti = 0; ti < 2; ++ti) {
        int nt = wid + ti * 8;
        int n = nt * 16 + n16;
        int nc = (n < NGATE) ? n : 0;
        bool valid = (nt < NTILES) && (n < NGATE);
        #pragma unroll
        for (int kt = 0; kt < 4; ++kt) {
            int base = nc * 104 + kt * 32 + q4 * 8;
            f32x4 wa = *(const f32x4*)&u.wstage[base];
            f32x4 wb = *(const f32x4*)&u.wstage[base + 4];
            short8 hi, lo;
            #pragma unroll
            for (int jj = 0; jj < 8; ++jj) {
                int kk = kt * 32 + q4 * 8 + jj;
                float w = (valid && kk < 100) ? ((jj < 4) ? wa[jj] : wb[jj - 4]) : 0.f;
                unsigned short h = f2bf(w);
                hi[jj] = (short)h;
                lo[jj] = (short)f2bf(w - bf2f(h));
            }
            b1h[ti][kt] = hi;
            b1l[ti][kt] = lo;
        }
    }
    __syncthreads();

    // ---- zero A buffers (rows 8-15 and k-padding stay zero forever) ----
    for (int i = tid; i < 16 * A0S; i += NTH) { u.s.A0hi[i] = 0; u.s.A0lo[i] = 0; }
    for (int i = tid; i < 16 * A1S; i += NTH) { u.s.A1hi[i] = 0; u.s.A1lo[i] = 0; }
    __syncthreads();

    // ---- per-cell-thread state + x prefetch ----
    float c0 = 0.f, cB = 0.f;
    float xr0 = 0.f, xr1 = 0.f, xr2 = 0.f;
    size_t xbase = 0;
    if (cellAct) {
        xbase = (size_t)(b0 + cb) * (TT * 3);
        xr0 = x[xbase + 0]; xr1 = x[xbase + 1]; xr2 = x[xbase + 2];
    }

    for (int t = 0; t < TT; ++t) {
        // ---- P1: layer0 MFMA  g = [h0] @ W_hh0^T (x-part added in P2) ----
        short8 a0h_[2], a0l_[2];
        #pragma unroll
        for (int kt = 0; kt < 2; ++kt) {
            a0h_[kt] = *(const short8*)&u.s.A0hi[n16 * A0S + kt * 32 + q4 * 8];
            a0l_[kt] = *(const short8*)&u.s.A0lo[n16 * A0S + kt * 32 + q4 * 8];
        }
        #pragma unroll
        for (int ti = 0; ti < 2; ++ti) {
            int nt = wid + ti * 8;
            if (nt < NTILES) {
                f32x4 acc = {0.f, 0.f, 0.f, 0.f};
                #pragma unroll
                for (int kt = 0; kt < 2; ++kt) {
                    acc = __builtin_amdgcn_mfma_f32_16x16x32_bf16(a0h_[kt], b0h[ti][kt], acc, 0, 0, 0);
                    acc = __builtin_amdgcn_mfma_f32_16x16x32_bf16(a0h_[kt], b0l[ti][kt], acc, 0, 0, 0);
                    acc = __builtin_amdgcn_mfma_f32_16x16x32_bf16(a0l_[kt], b0h[ti][kt], acc, 0, 0, 0);
                    acc = __builtin_amdgcn_mfma_f32_16x16x32_bf16(a0l_[kt], b0l[ti][kt], acc, 0, 0, 0);
                }
                *(f32x4*)&u.s.g[(nt * 16 + n16) * GS + q4 * 4] = acc;
            }
        }
        __syncthreads();

        // ---- P2: layer0 cell (adds x-part + bias on VALU) ----
        if (cellAct) {
            float p0 = u.s.g[(      cu) * GS + cb] + bias0g[0] + wx[0][0]*xr0 + wx[0][1]*xr1 + wx[0][2]*xr2;
            float p1 = u.s.g[( 50 + cu) * GS + cb] + bias0g[1] + wx[1][0]*xr0 + wx[1][1]*xr1 + wx[1][2]*xr2;
            float p2 = u.s.g[(100 + cu) * GS + cb] + bias0g[2] + wx[2][0]*xr0 + wx[2][1]*xr1 + wx[2][2]*xr2;
            float p3 = u.s.g[(150 + cu) * GS + cb] + bias0g[3] + wx[3][0]*xr0 + wx[3][1]*xr1 + wx[3][2]*xr2;
            float ii = fast_sigmoid(p0), ff = fast_sigmoid(p1);
            float gg = fast_tanh(p2),    oo = fast_sigmoid(p3);
            c0 = ff * c0 + ii * gg;
            float h = oo * fast_tanh(c0);
            unsigned short hh = f2bf(h);
            unsigned short hl = f2bf(h - bf2f(hh));
            u.s.A0hi[cb * A0S + cu] = hh;  u.s.A0lo[cb * A0S + cu] = hl;   // next-step layer0 input
            u.s.A1hi[cb * A1S + cu] = hh;  u.s.A1lo[cb * A1S + cu] = hl;   // this-step layer1 input
            int tn = (t + 1 < TT) ? (t + 1) : (TT - 1);
            xr0 = x[xbase + tn * 3 + 0];
            xr1 = x[xbase + tn * 3 + 1];
            xr2 = x[xbase + tn * 3 + 2];
        }
        __syncthreads();

        // ---- P3: layer1 MFMA  g = [h1_t | hB] @ [W_ih1|W_hh1]^T ----
        short8 a1h_[4], a1l_[4];
        #pragma unroll
        for (int kt = 0; kt < 4; ++kt) {
            a1h_[kt] = *(const short8*)&u.s.A1hi[n16 * A1S + kt * 32 + q4 * 8];
            a1l_[kt] = *(const short8*)&u.s.A1lo[n16 * A1S + kt * 32 + q4 * 8];
        }
        #pragma unroll
        for (int ti = 0; ti < 2; ++ti) {
            int nt = wid + ti * 8;
            if (nt < NTILES) {
                f32x4 acc = {0.f, 0.f, 0.f, 0.f};
                #pragma unroll
                for (int kt = 0; kt < 4; ++kt) {
                    acc = __builtin_amdgcn_mfma_f32_16x16x32_bf16(a1h_[kt], b1h[ti][kt], acc, 0, 0, 0);
                    acc = __builtin_amdgcn_mfma_f32_16x16x32_bf16(a1h_[kt], b1l[ti][kt], acc, 0, 0, 0);
                    acc = __builtin_amdgcn_mfma_f32_16x16x32_bf16(a1l_[kt], b1h[ti][kt], acc, 0, 0, 0);
                    acc = __builtin_amdgcn_mfma_f32_16x16x32_bf16(a1l_[kt], b1l[ti][kt], acc, 0, 0, 0);
                }
                *(f32x4*)&u.s.g[(nt * 16 + n16) * GS + q4 * 4] = acc;
            }
        }
        __syncthreads();

        // ---- P4: layer1 cell ----
        if (cellAct) {
            float p0 = u.s.g[(      cu) * GS + cb] + bias1g[0];
            float p1 = u.s.g[( 50 + cu) * GS + cb] + bias1g[1];
            float p2 = u.s.g[(100 + cu) * GS + cb] + bias1g[2];
            float p3 = u.s.g[(150 + cu) * GS + cb] + bias1g[3];
            float ii = fast_sigmoid(p0), ff = fast_sigmoid(p1);
            float gg = fast_tanh(p2),    oo = fast_sigmoid(p3);
            cB = ff * cB + ii * gg;
            float h = oo * fast_tanh(cB);
            unsigned short hh = f2bf(h);
            unsigned short hl = f2bf(h - bf2f(hh));
            u.s.A1hi[cb * A1S + 50 + cu] = hh;   // next-step hB
            u.s.A1lo[cb * A1S + 50 + cu] = hl;
            if (t == TT - 1) u.s.hBf[cb * 52 + cu] = h;
        }
        __syncthreads();
    }

    // ---- final FC: out[b] = hB @ fc_w^T + fc_b ----
    if (tid < NB * 3) {
        int bb = tid / 3, o = tid - bb * 3;
        float a = fc_b[o];
        #pragma unroll
        for (int uu = 0; uu < HH; ++uu)
            a += u.s.hBf[bb * 52 + uu] * fc_w[o * HH + uu];
        out[(size_t)(b0 + bb) * 3 + o] = a;
    }
}

extern "C" void kernel_launch(void* const* d_in, const int* in_sizes, int n_in,
                              void* d_out, int out_size, void* d_ws, size_t ws_size,
                              hipStream_t stream) {
    const float* x     = (const float*)d_in[0];
    const float* W_ih0 = (const float*)d_in[1];
    const float* W_hh0 = (const float*)d_in[2];
    const float* b_ih0 = (const float*)d_in[3];
    const float* b_hh0 = (const float*)d_in[4];
    const float* W_ih1 = (const float*)d_in[5];
    const float* W_hh1 = (const float*)d_in[6];
    const float* b_ih1 = (const float*)d_in[7];
    const float* b_hh1 = (const float*)d_in[8];
    const float* fc_w  = (const float*)d_in[9];
    const float* fc_b  = (const float*)d_in[10];
    float* out = (float*)d_out;

    const int B = 2048;
    dim3 grid(B / NB), block(NTH);
    lstm_mfma<<<grid, block, 0, stream>>>(
        x, W_ih0, W_hh0, b_ih0, b_hh0, W_ih1, W_hh1, b_ih1, b_hh1, fc_w, fc_b, out);
}

// Round 4
// 1024.863 us; speedup vs baseline: 18.1669x; 1.5852x over previous
//
#include <hip/hip_runtime.h>

#define HH 50
#define NGATE 200      // 4*H gate rows
#define NB 8           // batch elements per block
#define TT 512
#define NTH 512
#define NTILES 13      // ceil(200/16)
#define A0S 72         // shorts/row: 64 k-slots (54 used: h|x|1) + 8 pad = 144B
#define A1S 136        // shorts/row: 128 k-slots (101 used: h1|hB|1) + 8 pad = 272B
#define GS 20          // g row stride (floats), rows indexed by gate n

typedef __attribute__((ext_vector_type(8))) short short8;
typedef __attribute__((ext_vector_type(4))) float f32x4;

__device__ __forceinline__ unsigned short f2bf(float f) {
    unsigned int u = __float_as_uint(f);
    u += 0x7FFFu + ((u >> 16) & 1u);
    return (unsigned short)(u >> 16);
}
__device__ __forceinline__ float bf2f(unsigned short s) {
    return __uint_as_float(((unsigned int)s) << 16);
}
__device__ __forceinline__ float fast_sigmoid(float v) {
    v = fminf(fmaxf(v, -30.f), 30.f);
    return 1.f / (1.f + __expf(-v));
}
__device__ __forceinline__ float fast_tanh(float v) {
    v = fminf(fmaxf(v, -15.f), 15.f);
    float e = __expf(2.f * v);
    return (e - 1.f) / (e + 1.f);
}
__device__ __forceinline__ float cell_h(float pi, float pf, float pg, float po, float& c) {
    float ii = fast_sigmoid(pi), ff = fast_sigmoid(pf);
    float gg = fast_tanh(pg),    oo = fast_sigmoid(po);
    c = ff * c + ii * gg;
    return oo * fast_tanh(c);
}

__global__ __launch_bounds__(NTH, 2) void lstm_mfma_v2(
    const float* __restrict__ x,
    const float* __restrict__ W_ih0, const float* __restrict__ W_hh0,
    const float* __restrict__ b_ih0, const float* __restrict__ b_hh0,
    const float* __restrict__ W_ih1, const float* __restrict__ W_hh1,
    const float* __restrict__ b_ih1, const float* __restrict__ b_hh1,
    const float* __restrict__ fc_w, const float* __restrict__ fc_b,
    float* __restrict__ out)
{
    // A matrices hold bf16-split activations; K includes x and a constant-1
    // bias column so the MFMA produces the COMPLETE gate preactivation.
    __shared__ unsigned short A0hi[16 * A0S], A0lo[16 * A0S];
    __shared__ unsigned short A1hi[16 * A1S], A1lo[16 * A1S];
    __shared__ float g[208 * GS];      // gate preacts, [n][batch]
    __shared__ float hBf[8 * 52];      // final-step hB (fp32) for the FC

    const int tid = threadIdx.x;
    const int n16 = tid & 15;          // MFMA 16-lane index
    const int q4  = (tid >> 4) & 3;    // MFMA quad
    const int wid = tid >> 6;          // wave 0..7, owns N-tiles {wid, wid+8}
    const int b0  = blockIdx.x * NB;

    // ---- zero A state (rows 8..15 and k-pad stay zero forever) ----
    for (int i = tid; i < 16 * A0S; i += NTH) { A0hi[i] = 0; A0lo[i] = 0; }
    for (int i = tid; i < 16 * A1S; i += NTH) { A1hi[i] = 0; A1lo[i] = 0; }
    __syncthreads();

    // ---- constant-1 bias columns (batches 0..7 only) ----
    if (tid < NB) {
        A0hi[tid * A0S + 53]  = 0x3F80;   // bf16 1.0
        A1hi[tid * A1S + 100] = 0x3F80;
    }

    // ---- B-fragments: direct global gather into registers (prologue only) ----
    short8 b0h[2][2], b0l[2][2], b1h[2][4], b1l[2][4];
    #pragma unroll
    for (int ti = 0; ti < 2; ++ti) {
        const int nt = wid + ti * 8;
        const int n = nt * 16 + n16;
        const bool nv = (nt < NTILES) && (n < NGATE);
        #pragma unroll
        for (int kt = 0; kt < 2; ++kt) {     // layer0: K = [Whh0(50)|Wih0(3)|bias]
            short8 hi, lo;
            #pragma unroll
            for (int jj = 0; jj < 8; ++jj) {
                int k = kt * 32 + q4 * 8 + jj;
                float w = 0.f;
                if (nv) {
                    if (k < 50)      w = W_hh0[n * 50 + k];
                    else if (k < 53) w = W_ih0[n * 3 + (k - 50)];
                    else if (k == 53) w = b_ih0[n] + b_hh0[n];
                }
                unsigned short h = f2bf(w);
                hi[jj] = (short)h;
                lo[jj] = (short)f2bf(w - bf2f(h));
            }
            b0h[ti][kt] = hi; b0l[ti][kt] = lo;
        }
        #pragma unroll
        for (int kt = 0; kt < 4; ++kt) {     // layer1: K = [Wih1(50)|Whh1(50)|bias]
            short8 hi, lo;
            #pragma unroll
            for (int jj = 0; jj < 8; ++jj) {
                int k = kt * 32 + q4 * 8 + jj;
                float w = 0.f;
                if (nv) {
                    if (k < 50)       w = W_ih1[n * 50 + k];
                    else if (k < 100) w = W_hh1[n * 50 + (k - 50)];
                    else if (k == 100) w = b_ih1[n] + b_hh1[n];
                }
                unsigned short h = f2bf(w);
                hi[jj] = (short)h;
                lo[jj] = (short)f2bf(w - bf2f(h));
            }
            b1h[ti][kt] = hi; b1l[ti][kt] = lo;
        }
    }

    // ---- cell role: PAIR of adjacent hidden units -> all LDS writes are b32 ----
    const int cb  = tid & 7;           // batch (tid < 200)
    const int up  = tid >> 3;          // unit pair 0..24
    const int cu0 = 2 * up, cu1 = 2 * up + 1;
    float c0a = 0.f, c0b = 0.f, cBa = 0.f, cBb = 0.f;

    // ---- x-writer role: threads 448..471 own (batch, component) ----
    float xv = 0.f;
    size_t xbase = 0;
    int xb = 0, xc = 0;
    if (tid >= 448 && tid < 472) {
        int i = tid - 448;
        xb = i / 3; xc = i - xb * 3;
        xbase = (size_t)(b0 + xb) * (TT * 3);
        float x0 = x[xbase + xc];                    // t = 0
        unsigned short h = f2bf(x0);
        A0hi[xb * A0S + 50 + xc] = h;
        A0lo[xb * A0S + 50 + xc] = f2bf(x0 - bf2f(h));
        xv = x[xbase + 3 + xc];                      // prefetch t = 1
    }
    __syncthreads();

    for (int t = 0; t < TT; ++t) {
        // ======== P1: layer0 MFMA (full preact incl. x + bias) ========
        {
            short8 a0h_[2], a0l_[2];
            #pragma unroll
            for (int kt = 0; kt < 2; ++kt) {
                a0h_[kt] = *(const short8*)&A0hi[n16 * A0S + kt * 32 + q4 * 8];
                a0l_[kt] = *(const short8*)&A0lo[n16 * A0S + kt * 32 + q4 * 8];
            }
            #pragma unroll
            for (int ti = 0; ti < 2; ++ti) {
                int nt = wid + ti * 8;
                if (nt < NTILES) {
                    f32x4 acc = {0.f, 0.f, 0.f, 0.f};
                    #pragma unroll
                    for (int kt = 0; kt < 2; ++kt) {
                        acc = __builtin_amdgcn_mfma_f32_16x16x32_bf16(a0h_[kt], b0h[ti][kt], acc, 0, 0, 0);
                        acc = __builtin_amdgcn_mfma_f32_16x16x32_bf16(a0l_[kt], b0h[ti][kt], acc, 0, 0, 0);
                        acc = __builtin_amdgcn_mfma_f32_16x16x32_bf16(a0h_[kt], b0l[ti][kt], acc, 0, 0, 0);
                    }
                    if (q4 < 2)   // only batches 0..7 carry data
                        *(f32x4*)&g[(nt * 16 + n16) * GS + q4 * 4] = acc;
                }
            }
        }
        __syncthreads();

        // ======== P2: layer0 cell (pure g->act->h) + x staging ========
        if (tid < 200) {
            float h0 = cell_h(g[cu0 * GS + cb],        g[(cu0 + 50) * GS + cb],
                              g[(cu0 + 100) * GS + cb], g[(cu0 + 150) * GS + cb], c0a);
            float h1 = cell_h(g[cu1 * GS + cb],        g[(cu1 + 50) * GS + cb],
                              g[(cu1 + 100) * GS + cb], g[(cu1 + 150) * GS + cb], c0b);
            unsigned short h0h = f2bf(h0), h1h = f2bf(h1);
            unsigned int vhi = (unsigned int)h0h | ((unsigned int)h1h << 16);
            unsigned int vlo = (unsigned int)f2bf(h0 - bf2f(h0h))
                             | ((unsigned int)f2bf(h1 - bf2f(h1h)) << 16);
            *(unsigned int*)&A0hi[cb * A0S + cu0] = vhi;   // layer0 recurrent input
            *(unsigned int*)&A0lo[cb * A0S + cu0] = vlo;
            *(unsigned int*)&A1hi[cb * A1S + cu0] = vhi;   // layer1 input this step
            *(unsigned int*)&A1lo[cb * A1S + cu0] = vlo;
        } else if (tid >= 448 && tid < 472) {
            unsigned short h = f2bf(xv);                   // x(t+1)
            A0hi[xb * A0S + 50 + xc] = h;
            A0lo[xb * A0S + 50 + xc] = f2bf(xv - bf2f(h));
            int tn = (t + 2 < TT) ? (t + 2) : (TT - 1);
            xv = x[xbase + tn * 3 + xc];
        }
        __syncthreads();

        // ======== P3: layer1 MFMA ========
        {
            short8 a1h_[4], a1l_[4];
            #pragma unroll
            for (int kt = 0; kt < 4; ++kt) {
                a1h_[kt] = *(const short8*)&A1hi[n16 * A1S + kt * 32 + q4 * 8];
                a1l_[kt] = *(const short8*)&A1lo[n16 * A1S + kt * 32 + q4 * 8];
            }
            #pragma unroll
            for (int ti = 0; ti < 2; ++ti) {
                int nt = wid + ti * 8;
                if (nt < NTILES) {
                    f32x4 acc = {0.f, 0.f, 0.f, 0.f};
                    #pragma unroll
                    for (int kt = 0; kt < 4; ++kt) {
                        acc = __builtin_amdgcn_mfma_f32_16x16x32_bf16(a1h_[kt], b1h[ti][kt], acc, 0, 0, 0);
                        acc = __builtin_amdgcn_mfma_f32_16x16x32_bf16(a1l_[kt], b1h[ti][kt], acc, 0, 0, 0);
                        acc = __builtin_amdgcn_mfma_f32_16x16x32_bf16(a1h_[kt], b1l[ti][kt], acc, 0, 0, 0);
                    }
                    if (q4 < 2)
                        *(f32x4*)&g[(nt * 16 + n16) * GS + q4 * 4] = acc;
                }
            }
        }
        __syncthreads();

        // ======== P4: layer1 cell ========
        if (tid < 200) {
            float h0 = cell_h(g[cu0 * GS + cb],        g[(cu0 + 50) * GS + cb],
                              g[(cu0 + 100) * GS + cb], g[(cu0 + 150) * GS + cb], cBa);
            float h1 = cell_h(g[cu1 * GS + cb],        g[(cu1 + 50) * GS + cb],
                              g[(cu1 + 100) * GS + cb], g[(cu1 + 150) * GS + cb], cBb);
            unsigned short h0h = f2bf(h0), h1h = f2bf(h1);
            unsigned int vhi = (unsigned int)h0h | ((unsigned int)h1h << 16);
            unsigned int vlo = (unsigned int)f2bf(h0 - bf2f(h0h))
                             | ((unsigned int)f2bf(h1 - bf2f(h1h)) << 16);
            *(unsigned int*)&A1hi[cb * A1S + 50 + cu0] = vhi;  // next-step hB
            *(unsigned int*)&A1lo[cb * A1S + 50 + cu0] = vlo;
            if (t == TT - 1) {
                hBf[cb * 52 + cu0] = h0;
                hBf[cb * 52 + cu1] = h1;
            }
        }
        __syncthreads();
    }

    // ======== final FC ========
    if (tid < NB * 3) {
        int bb = tid / 3, o = tid - bb * 3;
        float a = fc_b[o];
        #pragma unroll
        for (int uu = 0; uu < HH; ++uu)
            a += hBf[bb * 52 + uu] * fc_w[o * HH + uu];
        out[(size_t)(b0 + bb) * 3 + o] = a;
    }
}

extern "C" void kernel_launch(void* const* d_in, const int* in_sizes, int n_in,
                              void* d_out, int out_size, void* d_ws, size_t ws_size,
                              hipStream_t stream) {
    const float* x     = (const float*)d_in[0];
    const float* W_ih0 = (const float*)d_in[1];
    const float* W_hh0 = (const float*)d_in[2];
    const float* b_ih0 = (const float*)d_in[3];
    const float* b_hh0 = (const float*)d_in[4];
    const float* W_ih1 = (const float*)d_in[5];
    const float* W_hh1 = (const float*)d_in[6];
    const float* b_ih1 = (const float*)d_in[7];
    const float* b_hh1 = (const float*)d_in[8];
    const float* fc_w  = (const float*)d_in[9];
    const float* fc_b  = (const float*)d_in[10];
    float* out = (float*)d_out;

    const int B = 2048;
    dim3 grid(B / NB), block(NTH);
    lstm_mfma_v2<<<grid, block, 0, stream>>>(
        x, W_ih0, W_hh0, b_ih0, b_hh0, W_ih1, W_hh1, b_ih1, b_hh1, fc_w, fc_b, out);
}